// Round 6
// baseline (1704.467 us; speedup 1.0000x reference)
//
#include <hip/hip_runtime.h>

#define T_DIM 64
#define N_DIM 2000
#define C_DIM 64
#define E_DIM 32000
#define ROWS (T_DIM * N_DIM)   // 128000
#define BN_EPS 1e-5f

typedef short s8v __attribute__((ext_vector_type(8)));
typedef float f4v __attribute__((ext_vector_type(4)));

__device__ __forceinline__ ushort f2b(float f) {
    unsigned u = __float_as_uint(f);
    unsigned r = u + 0x7FFF + ((u >> 16) & 1);
    return (ushort)(r >> 16);
}

// ---------------- prep: single block does zero+histogram+dinv+scan+self+cursor ----------------
__global__ __launch_bounds__(1024) void k_prep1(
    const int* __restrict__ ei, float* __restrict__ dinv_g,
    int* __restrict__ offs, int* __restrict__ cursor,
    int2* __restrict__ edat, float* __restrict__ a_arr,
    float* __restrict__ bnstats) {
    __shared__ int hist[2048];
    __shared__ int sc[2048], sc2[2048];
    __shared__ float sdv[2048];
    int tid = threadIdx.x;
    for (int i = tid; i < 2048; i += 1024) hist[i] = 0;
    if (tid < 128) bnstats[tid] = 0.f;
    __syncthreads();
    for (int e = tid; e < E_DIM; e += 1024) atomicAdd(&hist[ei[E_DIM + e]], 1);
    __syncthreads();
    for (int i = tid; i < 2048; i += 1024) {
        int d = (i < N_DIM) ? hist[i] : 0;
        sc[i] = (i < N_DIM) ? (d + 1) : 0;
        float dv = (i < N_DIM) ? rsqrtf((float)(d + 1)) : 0.f;
        sdv[i] = dv;
        if (i < N_DIM) dinv_g[i] = dv;
    }
    __syncthreads();
    int* s = sc; int* d = sc2;
    for (int off = 1; off < 2048; off <<= 1) {
        for (int i = tid; i < 2048; i += 1024)
            d[i] = s[i] + ((i >= off) ? s[i - off] : 0);
        __syncthreads();
        int* t = s; s = d; d = t;
    }
    for (int i = tid; i < 2048; i += 1024) {
        if (i <= N_DIM) offs[i] = (i == 0) ? 0 : s[i - 1];
        if (i < N_DIM) {
            int off = (i == 0) ? 0 : s[i - 1];
            float dv = sdv[i];
            edat[off] = make_int2(i, __float_as_int(dv * dv));
            cursor[i] = 1;
            a_arr[i] = dv * dv;
        }
    }
}

__global__ void k_fill(const int* __restrict__ ei, const int* __restrict__ offs,
                       const float* __restrict__ dinv, int* __restrict__ cursor,
                       int2* __restrict__ edat, float* __restrict__ a_arr) {
    int e = blockIdx.x * 256 + threadIdx.x;              // < 32000 exactly
    int s = ei[e];
    int d = ei[E_DIM + e];
    int p = atomicAdd(&cursor[d], 1);
    float w = dinv[s] * dinv[d];
    edat[offs[d] + p] = make_int2(s, __float_as_int(w));
    atomicAdd(&a_arr[d], w);
}

// ---------------- weights: single block. Wc1 in LDS, composed K=5 W12f + variants + u/v ----------------
__global__ __launch_bounds__(1024) void k_wprep(
    const float* __restrict__ c1w, const float* __restrict__ c1b,
    const float* __restrict__ gw, const float* __restrict__ gb,
    const float* __restrict__ c2w, const float* __restrict__ c2b,
    ushort* __restrict__ W12f, float* __restrict__ uvec, float* __restrict__ vvec) {
    __shared__ float Wc1s[12288];   // [k1][ik][c], 48 KB
    __shared__ float bucs[64];
    int tid = threadIdx.x;
    // phase A: Wc1[k1][ik][c] = sum_j c1w[j,ik,k1]*gw[j,c]
    for (int idx = tid; idx < 12288; idx += 1024) {
        int k1 = idx >> 12, ik = (idx >> 6) & 63, c = idx & 63;
        float s = 0.f;
        for (int j = 0; j < 64; ++j)
            s += c1w[j * 192 + ik * 3 + k1] * gw[j * 64 + c];
        Wc1s[idx] = s;
    }
    if (tid < 64) {
        float bs = 0.f;
        for (int j = 0; j < 64; ++j) bs += c1b[j] * gw[j * 64 + tid];
        bucs[tid] = bs;
    }
    __syncthreads();
    // phase B1: main composed taps j=0..4 -> frag order
    for (int idx = tid; idx < 20480; idx += 1024) {
        int kk = idx >> 6, o = idx & 63;
        int j = kk >> 6, ik = kk & 63;
        float sum = 0.f;
        #pragma unroll
        for (int k1 = 0; k1 < 3; ++k1) {
            int k2 = j - k1;
            if (k2 >= 0 && k2 <= 2) {
                for (int c = 0; c < 64; ++c)
                    sum += Wc1s[k1 * 4096 + ik * 64 + c] * c2w[o * 192 + c * 3 + k2];
            }
        }
        int s = kk >> 5, q = (kk >> 3) & 3, jj = kk & 7, cc = o >> 4, m = o & 15;
        W12f[(((s * 4 + cc) * 64) + q * 16 + m) * 8 + jj] = f2b(sum);
    }
    // phase B2: tap-2 boundary variants (t=0 excludes (k1=2,k2=0); t=63 excludes (k1=0,k2=2))
    for (int idx = tid; idx < 8192; idx += 1024) {
        int var = idx >> 12;
        int ik = (idx >> 6) & 63, o = idx & 63;
        float sum = 0.f;
        for (int c = 0; c < 64; ++c) {
            float acc = Wc1s[1 * 4096 + ik * 64 + c] * c2w[o * 192 + c * 3 + 1];
            acc += (var == 0)
                ? Wc1s[0 * 4096 + ik * 64 + c] * c2w[o * 192 + c * 3 + 2]
                : Wc1s[2 * 4096 + ik * 64 + c] * c2w[o * 192 + c * 3 + 0];
            sum += acc;
        }
        int kk = 128 + ik;
        int s = kk >> 5, q = (kk >> 3) & 3, jj = kk & 7, cc = o >> 4, m = o & 15;
        int flat = (((s * 4 + cc) * 64) + q * 16 + m) * 8 + jj;   // in [8192,12288)
        W12f[flat + 12288 + var * 4096] = f2b(sum);               // t=0: [20480,24576), t=63: [24576,28672)
    }
    // phase B3: rank-1 bias tables u[3][64], v[3][64]
    if (tid < 192) {
        int cs = tid >> 6, o = tid & 63;
        float uu = 0.f, vv = 0.f;
        for (int c = 0; c < 64; ++c) {
            float wsum = c2w[o * 192 + c * 3 + 1];
            if (cs != 0) wsum += c2w[o * 192 + c * 3 + 0];
            if (cs != 2) wsum += c2w[o * 192 + c * 3 + 2];
            uu += bucs[c] * wsum;
            vv += gb[c] * wsum;
        }
        uvec[cs * 64 + o] = uu;
        vvec[cs * 64 + o] = vv + c2b[o];
    }
}

// ---------------- Agg(x): CSR gather, x fp32 -> xg bf16, 8 edge-slots, 2-way ILP ----------------
__global__ __launch_bounds__(256) void k_gather(
    const float* __restrict__ x, const int* __restrict__ offs,
    const int2* __restrict__ edat, ushort* __restrict__ xg) {
    int unit = blockIdx.x * 4 + (threadIdx.x >> 6);   // one wave per (t,n)
    int lane = threadIdx.x & 63;
    int g = lane >> 3;            // edge slot 0..7
    int c8 = (lane & 7) * 8;      // channel base
    int t = unit / N_DIM;
    int n = unit - t * N_DIM;
    int beg = offs[n], end = offs[n + 1];
    const float* base = x + (size_t)t * N_DIM * 64 + c8;

    float a[8] = {0.f, 0.f, 0.f, 0.f, 0.f, 0.f, 0.f, 0.f};
    int j = beg + g;
    for (; j + 8 < end; j += 16) {
        int2 e1 = edat[j];
        int2 e2 = edat[j + 8];
        const float* p1 = base + (size_t)e1.x * 64;
        const float* p2 = base + (size_t)e2.x * 64;
        float4 v0 = *(const float4*)p1;
        float4 v1 = *(const float4*)(p1 + 4);
        float4 u0 = *(const float4*)p2;
        float4 u1 = *(const float4*)(p2 + 4);
        float w1 = __int_as_float(e1.y), w2 = __int_as_float(e2.y);
        a[0] += w1 * v0.x + w2 * u0.x; a[1] += w1 * v0.y + w2 * u0.y;
        a[2] += w1 * v0.z + w2 * u0.z; a[3] += w1 * v0.w + w2 * u0.w;
        a[4] += w1 * v1.x + w2 * u1.x; a[5] += w1 * v1.y + w2 * u1.y;
        a[6] += w1 * v1.z + w2 * u1.z; a[7] += w1 * v1.w + w2 * u1.w;
    }
    if (j < end) {
        int2 e = edat[j];
        float w = __int_as_float(e.y);
        const float* p = base + (size_t)e.x * 64;
        float4 v0 = *(const float4*)p;
        float4 v1 = *(const float4*)(p + 4);
        a[0] += w * v0.x; a[1] += w * v0.y; a[2] += w * v0.z; a[3] += w * v0.w;
        a[4] += w * v1.x; a[5] += w * v1.y; a[6] += w * v1.z; a[7] += w * v1.w;
    }
    #pragma unroll
    for (int d = 8; d <= 32; d <<= 1)
        #pragma unroll
        for (int i = 0; i < 8; ++i) a[i] += __shfl_xor(a[i], d);

    if (g == 0) {
        s8v pk;
        #pragma unroll
        for (int i = 0; i < 8; ++i) pk[i] = (short)f2b(a[i]);
        *(s8v*)&xg[(size_t)unit * 64 + c8] = pk;
    }
}

// ---------------- fused K=5 conv GEMM: W in LDS, 2 strips (32 rows) per wave ----------------
// lane(q,m): D transposed via operand swap -> lane holds out[row0+m][c*16+q*4 ..+3]
__global__ __launch_bounds__(256) void k_conv(
    const ushort* __restrict__ xg, const ushort* __restrict__ Wf,
    const float* __restrict__ uvec, const float* __restrict__ vvec,
    const float* __restrict__ a_arr, float* __restrict__ out,
    float* __restrict__ bnstats) {
    __shared__ __align__(16) ushort Wl[20480];   // 40 KB, exactly; sb aliased in after use
    int tid = threadIdx.x;
    // stage main W taps: 2560 x 16B chunks
    #pragma unroll
    for (int o = 0; o < 10; ++o) {
        int idx = tid + o * 256;
        *(s8v*)&Wl[idx * 8] = *(const s8v*)&Wf[idx * 8];
    }
    __syncthreads();

    int wv = tid >> 6, lane = tid & 63;
    int m = lane & 15, q = lane >> 4;
    int strip0 = blockIdx.x * 8 + wv * 2;     // wave covers strips strip0, strip0+1
    int t0 = strip0 / 125;
    int t1 = (strip0 + 1) / 125;

    f4v acc[2][4];
    #pragma unroll
    for (int st = 0; st < 2; ++st)
        #pragma unroll
        for (int c = 0; c < 4; ++c) acc[st][c] = (f4v){0.f, 0.f, 0.f, 0.f};

    const ushort* abase = xg + (size_t)(strip0 * 16 + m) * 64 + q * 8;

    if (t0 >= 2 && t1 <= 61) {
        // interior: full 5-tap, compile-time unrolled
        #pragma unroll
        for (int j = 0; j < 5; ++j) {
            #pragma unroll
            for (int s = 0; s < 2; ++s) {
                const ushort* ab = abase + (ptrdiff_t)(j - 2) * N_DIM * 64 + s * 32;
                s8v af0 = *(const s8v*)ab;
                s8v af1 = *(const s8v*)(ab + 1024);    // +16 rows
                int sg = j * 2 + s;
                #pragma unroll
                for (int c = 0; c < 4; ++c) {
                    s8v bf = *(const s8v*)&Wl[((sg * 4 + c) * 64 + lane) * 8];
                    acc[0][c] = __builtin_amdgcn_mfma_f32_16x16x32_bf16(bf, af0, acc[0][c], 0, 0, 0);
                    acc[1][c] = __builtin_amdgcn_mfma_f32_16x16x32_bf16(bf, af1, acc[1][c], 0, 0, 0);
                }
            }
        }
    } else {
        // boundary: per-strip runtime taps; t in {0,63} uses variant tap-2 from global
        for (int st = 0; st < 2; ++st) {
            int strip = strip0 + st;
            int t = strip / 125;
            int jlo = (t == 0) ? 2 : ((t == 1) ? 1 : 0);
            int jhi = (t == 63) ? 2 : ((t == 62) ? 3 : 4);
            int tap2off = (t == 0) ? 12288 : ((t == 63) ? 16384 : 0);
            const ushort* ab0 = abase + (size_t)st * 1024;
            for (int j = jlo; j <= jhi; ++j) {
                bool usevar = (j == 2) && (tap2off != 0);
                #pragma unroll
                for (int s = 0; s < 2; ++s) {
                    s8v af = *(const s8v*)(ab0 + (ptrdiff_t)(j - 2) * N_DIM * 64 + s * 32);
                    int sg = j * 2 + s;
                    #pragma unroll
                    for (int c = 0; c < 4; ++c) {
                        int fi = ((sg * 4 + c) * 64 + lane) * 8;
                        s8v bf = usevar ? *(const s8v*)(Wf + tap2off + fi)
                                        : *(const s8v*)&Wl[fi];
                        acc[st][c] = __builtin_amdgcn_mfma_f32_16x16x32_bf16(bf, af, acc[st][c], 0, 0, 0);
                    }
                }
            }
        }
    }

    // epilogue: bias + store + BN partials (both strips into one ps/pq)
    float ps[16], pq[16];
    #pragma unroll
    for (int i = 0; i < 16; ++i) { ps[i] = 0.f; pq[i] = 0.f; }
    #pragma unroll
    for (int st = 0; st < 2; ++st) {
        int strip = strip0 + st;
        int t = strip / 125;
        int sloc = strip - t * 125;
        int row0 = strip * 16;
        int bcase = (t == 0) ? 0 : ((t == 63) ? 2 : 1);
        float av = a_arr[sloc * 16 + m];
        #pragma unroll
        for (int c = 0; c < 4; ++c) {
            float4 u4 = *(const float4*)&uvec[bcase * 64 + c * 16 + q * 4];
            float4 v4 = *(const float4*)&vvec[bcase * 64 + c * 16 + q * 4];
            float4 r;
            r.x = acc[st][c][0] + av * u4.x + v4.x;
            r.y = acc[st][c][1] + av * u4.y + v4.y;
            r.z = acc[st][c][2] + av * u4.z + v4.z;
            r.w = acc[st][c][3] + av * u4.w + v4.w;
            *(float4*)&out[(size_t)(row0 + m) * 64 + c * 16 + q * 4] = r;
            ps[c * 4 + 0] += r.x; ps[c * 4 + 1] += r.y; ps[c * 4 + 2] += r.z; ps[c * 4 + 3] += r.w;
            pq[c * 4 + 0] += r.x * r.x; pq[c * 4 + 1] += r.y * r.y;
            pq[c * 4 + 2] += r.z * r.z; pq[c * 4 + 3] += r.w * r.w;
        }
    }
    #pragma unroll
    for (int d = 1; d <= 8; d <<= 1) {
        #pragma unroll
        for (int i = 0; i < 16; ++i) {
            ps[i] += __shfl_xor(ps[i], d);
            pq[i] += __shfl_xor(pq[i], d);
        }
    }
    __syncthreads();                 // Wl dead everywhere; reuse as sb
    float* sb = (float*)Wl;
    if (tid < 128) sb[tid] = 0.f;
    __syncthreads();
    if (m == 0) {
        #pragma unroll
        for (int i = 0; i < 16; ++i) {
            int ch = (i >> 2) * 16 + q * 4 + (i & 3);
            atomicAdd(&sb[ch], ps[i]);
            atomicAdd(&sb[64 + ch], pq[i]);
        }
    }
    __syncthreads();
    if (tid < 128) atomicAdd(&bnstats[tid], sb[tid]);
}

// ---------------- BN + ReLU, in place; 8000 blocks cover exactly ----------------
__global__ __launch_bounds__(256) void k_bn(float* __restrict__ io,
                                            const float* __restrict__ bnstats,
                                            const float* __restrict__ gamma,
                                            const float* __restrict__ beta) {
    __shared__ float sscale[64], sshift[64];
    int tid = threadIdx.x;
    if (tid < 64) {
        float m = bnstats[tid] * (1.0f / ROWS);
        float v = bnstats[64 + tid] * (1.0f / ROWS) - m * m;
        float sc = gamma[tid] * rsqrtf(v + BN_EPS);
        sscale[tid] = sc;
        sshift[tid] = beta[tid] - m * sc;
    }
    __syncthreads();
    int i4 = blockIdx.x * 256 + tid;     // < 2,048,000 exactly
    float4 v = *(const float4*)(io + (size_t)i4 * 4);
    int c = (i4 * 4) & 63;
    v.x = fmaxf(v.x * sscale[c + 0] + sshift[c + 0], 0.f);
    v.y = fmaxf(v.y * sscale[c + 1] + sshift[c + 1], 0.f);
    v.z = fmaxf(v.z * sscale[c + 2] + sshift[c + 2], 0.f);
    v.w = fmaxf(v.w * sscale[c + 3] + sshift[c + 3], 0.f);
    *(float4*)(io + (size_t)i4 * 4) = v;
}

extern "C" void kernel_launch(void* const* d_in, const int* in_sizes, int n_in,
                              void* d_out, int out_size, void* d_ws, size_t ws_size,
                              hipStream_t stream) {
    const float* x   = (const float*)d_in[0];
    const int*   ei  = (const int*)d_in[1];
    const float* c1w = (const float*)d_in[2];
    const float* c1b = (const float*)d_in[3];
    const float* gw  = (const float*)d_in[4];
    const float* gb  = (const float*)d_in[5];
    const float* c2w = (const float*)d_in[6];
    const float* c2b = (const float*)d_in[7];
    const float* bng = (const float*)d_in[8];
    const float* bnb = (const float*)d_in[9];
    float* out = (float*)d_out;

    // workspace layout
    ushort* xg   = (ushort*)d_ws;                 // ROWS*64 bf16 = 16.4 MB
    ushort* W12f = xg + (size_t)ROWS * 64;        // 28672 (20480 main + 2x4096 variants)
    float*  fb   = (float*)(W12f + 28672);
    float*  uvec    = fb;                         // 192
    float*  vvec    = uvec + 192;                 // 192
    float*  a_arr   = vvec + 192;                 // 2000
    float*  dinv    = a_arr + 2000;               // 2000
    float*  bnstats = dinv + 2000;                // 128
    int*    offs    = (int*)(bnstats + 128);      // 2001
    int*    cursor  = offs + 2001;                // 2000
    int*    iend    = cursor + 2000;
    int2*   edat    = (int2*)((char*)iend + (((size_t)iend) % 8 ? 4 : 0)); // 34000 int2

    k_prep1<<<1, 1024, 0, stream>>>(ei, dinv, offs, cursor, edat, a_arr, bnstats);
    k_fill<<<125, 256, 0, stream>>>(ei, offs, dinv, cursor, edat, a_arr);
    k_wprep<<<1, 1024, 0, stream>>>(c1w, c1b, gw, gb, c2w, c2b, W12f, uvec, vvec);

    // stage 1: Agg(x) -> xg bf16
    k_gather<<<ROWS / 4, 256, 0, stream>>>(x, offs, edat, xg);
    // stage 2: composed K=5 conv + rank-1 bias + BN stats
    k_conv<<<1000, 256, 0, stream>>>(xg, W12f, uvec, vvec, a_arr, out, bnstats);
    // stage 3: BN + ReLU in place
    k_bn<<<8000, 256, 0, stream>>>(out, bnstats, bng, bnb);
}

// Round 7
// 272.577 us; speedup vs baseline: 6.2532x; 6.2532x over previous
//
#include <hip/hip_runtime.h>

#define T_DIM 64
#define N_DIM 2000
#define C_DIM 64
#define E_DIM 32000
#define ROWS (T_DIM * N_DIM)   // 128000
#define BN_EPS 1e-5f

typedef short s8v __attribute__((ext_vector_type(8)));
typedef float f4v __attribute__((ext_vector_type(4)));

__device__ __forceinline__ ushort f2b(float f) {
    unsigned u = __float_as_uint(f);
    unsigned r = u + 0x7FFF + ((u >> 16) & 1);
    return (ushort)(r >> 16);
}

// ---------------- prep (parallel; round-5 structure) ----------------

// blocks 0..124: degree atomics.  blocks 125..172: Wc1[k1][ik][c] = sum_j c1w[j,ik,k1]*gw[j,c]
__global__ void k_pre1(const int* __restrict__ ei, const float* __restrict__ c1w,
                       const float* __restrict__ gw, int* __restrict__ deg,
                       float* __restrict__ Wc1) {
    if (blockIdx.x < 125) {
        int e = blockIdx.x * 256 + threadIdx.x;          // < 32000 exactly
        atomicAdd(&deg[ei[E_DIM + e]], 1);
    } else {
        int gid = (blockIdx.x - 125) * 256 + threadIdx.x; // < 12288 exactly
        int k1 = gid >> 12, ik = (gid >> 6) & 63, c = gid & 63;
        float s = 0.f;
        for (int j = 0; j < 64; ++j)
            s += c1w[j * 192 + ik * 3 + k1] * gw[j * 64 + c];
        Wc1[gid] = s;
    }
}

// single block: dinv, exclusive scan of (deg+1) -> offs, self-edges, cursor, a_n seed, bnstats zero
__global__ __launch_bounds__(1024) void k_pre2(
    const int* __restrict__ deg, float* __restrict__ dinv_g,
    int* __restrict__ offs, int* __restrict__ cursor,
    int2* __restrict__ edat, float* __restrict__ a_arr,
    float* __restrict__ bnstats) {
    __shared__ int sa[2048], sbuf[2048];
    __shared__ float sdinv[2048];
    int tid = threadIdx.x;
    if (tid < 128) bnstats[tid] = 0.f;
    for (int i = tid; i < 2048; i += 1024) {
        int d = (i < N_DIM) ? deg[i] : 0;
        sa[i] = (i < N_DIM) ? (d + 1) : 0;
        float dv = (i < N_DIM) ? rsqrtf((float)(d + 1)) : 0.f;
        sdinv[i] = dv;
        if (i < N_DIM) dinv_g[i] = dv;
    }
    __syncthreads();
    int* s = sa; int* d = sbuf;
    for (int off = 1; off < 2048; off <<= 1) {
        for (int i = tid; i < 2048; i += 1024)
            d[i] = s[i] + ((i >= off) ? s[i - off] : 0);
        __syncthreads();
        int* t = s; s = d; d = t;
    }
    for (int i = tid; i < 2048; i += 1024) {
        if (i <= N_DIM) offs[i] = (i == 0) ? 0 : s[i - 1];
        if (i < N_DIM) {
            int off = (i == 0) ? 0 : s[i - 1];
            float dv = sdinv[i];
            edat[off] = make_int2(i, __float_as_int(dv * dv));
            cursor[i] = 1;
            a_arr[i] = dv * dv;
        }
    }
}

__global__ void k_fill(const int* __restrict__ ei, const int* __restrict__ offs,
                       const float* __restrict__ dinv, int* __restrict__ cursor,
                       int2* __restrict__ edat, float* __restrict__ a_arr) {
    int e = blockIdx.x * 256 + threadIdx.x;              // < 32000 exactly
    int s = ei[e];
    int d = ei[E_DIM + e];
    int p = atomicAdd(&cursor[d], 1);
    float w = dinv[s] * dinv[d];
    edat[offs[d] + p] = make_int2(s, __float_as_int(w));
    atomicAdd(&a_arr[d], w);
}

// W12f: composed K=5 conv weights (bf16, MFMA B-frag order), 20480 shorts,
// + tap-2 boundary variants: t=0 at [20480,24576), t=63 at [24576,28672)
// + u[3][64], v[3][64].
// Boundary math: conv2's padding zeroes z[-1]/z[64] wholesale, so at t=0 the
// (k1=2,k2=0) path is excluded from tap j=2; at t=63 the (k1=0,k2=2) path.
__global__ void k_pre3(const float* __restrict__ Wc1, const float* __restrict__ c2w,
                       const float* __restrict__ c1b, const float* __restrict__ gw,
                       const float* __restrict__ gb, const float* __restrict__ c2b,
                       ushort* __restrict__ W12f, float* __restrict__ uvec,
                       float* __restrict__ vvec) {
    int gid = blockIdx.x * 256 + threadIdx.x;   // 113*256 = 28928
    if (gid < 320 * 64) {
        int kk = gid >> 6, o = gid & 63;
        int j = kk >> 6, ik = kk & 63;
        float sum = 0.f;
        #pragma unroll
        for (int k1 = 0; k1 < 3; ++k1) {
            int k2 = j - k1;
            if (k2 >= 0 && k2 <= 2) {
                for (int c = 0; c < 64; ++c)
                    sum += Wc1[k1 * 4096 + ik * 64 + c] * c2w[o * 192 + c * 3 + k2];
            }
        }
        int s = kk >> 5, q = (kk >> 3) & 3, jj = kk & 7, cc = o >> 4, m = o & 15;
        W12f[(((s * 4 + cc) * 64) + q * 16 + m) * 8 + jj] = f2b(sum);
    } else if (gid < 320 * 64 + 8192) {
        int idx = gid - 320 * 64;
        int var = idx >> 12;          // 0: t=0 variant, 1: t=63 variant
        int ik = (idx >> 6) & 63, o = idx & 63;
        float sum = 0.f;
        for (int c = 0; c < 64; ++c) {
            float acc = Wc1[1 * 4096 + ik * 64 + c] * c2w[o * 192 + c * 3 + 1];
            acc += (var == 0)
                ? Wc1[0 * 4096 + ik * 64 + c] * c2w[o * 192 + c * 3 + 2]
                : Wc1[2 * 4096 + ik * 64 + c] * c2w[o * 192 + c * 3 + 0];
            sum += acc;
        }
        int kk = 128 + ik;
        int s = kk >> 5, q = (kk >> 3) & 3, jj = kk & 7, cc = o >> 4, m = o & 15;
        int flat = (((s * 4 + cc) * 64) + q * 16 + m) * 8 + jj;   // in [8192,12288)
        W12f[flat - 8192 + 20480 + var * 4096] = f2b(sum);
    } else if (gid < 320 * 64 + 8192 + 192) {
        int idx = gid - 320 * 64 - 8192;
        int cs = idx >> 6, o = idx & 63;
        float uu = 0.f, vv = 0.f;
        for (int c = 0; c < 64; ++c) {
            float buc = 0.f;
            for (int jx = 0; jx < 64; ++jx) buc += c1b[jx] * gw[jx * 64 + c];
            float wsum = c2w[o * 192 + c * 3 + 1];
            if (cs != 0) wsum += c2w[o * 192 + c * 3 + 0];
            if (cs != 2) wsum += c2w[o * 192 + c * 3 + 2];
            uu += buc * wsum;
            vv += gb[c] * wsum;
        }
        uvec[cs * 64 + o] = uu;
        vvec[cs * 64 + o] = vv + c2b[o];
    }
}

// ---------------- Agg(x): CSR gather, x fp32 -> xg bf16, 8 edge-slots, 2-way ILP ----------------
__global__ __launch_bounds__(256) void k_gather(
    const float* __restrict__ x, const int* __restrict__ offs,
    const int2* __restrict__ edat, ushort* __restrict__ xg) {
    int unit = blockIdx.x * 4 + (threadIdx.x >> 6);   // one wave per (t,n)
    int lane = threadIdx.x & 63;
    int g = lane >> 3;            // edge slot 0..7
    int c8 = (lane & 7) * 8;      // channel base
    int t = unit / N_DIM;
    int n = unit - t * N_DIM;
    int beg = offs[n], end = offs[n + 1];
    const float* base = x + (size_t)t * N_DIM * 64 + c8;

    float a[8] = {0.f, 0.f, 0.f, 0.f, 0.f, 0.f, 0.f, 0.f};
    int j = beg + g;
    for (; j + 8 < end; j += 16) {
        int2 e1 = edat[j];
        int2 e2 = edat[j + 8];
        const float* p1 = base + (size_t)e1.x * 64;
        const float* p2 = base + (size_t)e2.x * 64;
        float4 v0 = *(const float4*)p1;
        float4 v1 = *(const float4*)(p1 + 4);
        float4 u0 = *(const float4*)p2;
        float4 u1 = *(const float4*)(p2 + 4);
        float w1 = __int_as_float(e1.y), w2 = __int_as_float(e2.y);
        a[0] += w1 * v0.x + w2 * u0.x; a[1] += w1 * v0.y + w2 * u0.y;
        a[2] += w1 * v0.z + w2 * u0.z; a[3] += w1 * v0.w + w2 * u0.w;
        a[4] += w1 * v1.x + w2 * u1.x; a[5] += w1 * v1.y + w2 * u1.y;
        a[6] += w1 * v1.z + w2 * u1.z; a[7] += w1 * v1.w + w2 * u1.w;
    }
    if (j < end) {
        int2 e = edat[j];
        float w = __int_as_float(e.y);
        const float* p = base + (size_t)e.x * 64;
        float4 v0 = *(const float4*)p;
        float4 v1 = *(const float4*)(p + 4);
        a[0] += w * v0.x; a[1] += w * v0.y; a[2] += w * v0.z; a[3] += w * v0.w;
        a[4] += w * v1.x; a[5] += w * v1.y; a[6] += w * v1.z; a[7] += w * v1.w;
    }
    #pragma unroll
    for (int d = 8; d <= 32; d <<= 1)
        #pragma unroll
        for (int i = 0; i < 8; ++i) a[i] += __shfl_xor(a[i], d);

    if (g == 0) {
        s8v pk;
        #pragma unroll
        for (int i = 0; i < 8; ++i) pk[i] = (short)f2b(a[i]);
        *(s8v*)&xg[(size_t)unit * 64 + c8] = pk;
    }
}

// ---------------- fused K=5 conv GEMM: W in LDS, 2 strips (32 rows) per wave ----------------
// lane(q,m): D transposed via operand swap -> lane holds out[row0+m][c*16+q*4 ..+3]
__global__ __launch_bounds__(256) void k_conv(
    const ushort* __restrict__ xg, const ushort* __restrict__ Wf,
    const float* __restrict__ uvec, const float* __restrict__ vvec,
    const float* __restrict__ a_arr, float* __restrict__ out,
    float* __restrict__ bnstats) {
    __shared__ __align__(16) ushort Wl[20480];   // 40 KB; reused as sb after MFMA
    int tid = threadIdx.x;
    #pragma unroll
    for (int o = 0; o < 10; ++o) {
        int idx = tid + o * 256;
        *(s8v*)&Wl[idx * 8] = *(const s8v*)&Wf[idx * 8];
    }
    __syncthreads();

    int wv = tid >> 6, lane = tid & 63;
    int m = lane & 15, q = lane >> 4;
    int strip0 = blockIdx.x * 8 + wv * 2;     // wave covers strips strip0, strip0+1
    int t0 = strip0 / 125;
    int t1 = (strip0 + 1) / 125;

    f4v acc[2][4];
    #pragma unroll
    for (int st = 0; st < 2; ++st)
        #pragma unroll
        for (int c = 0; c < 4; ++c) acc[st][c] = (f4v){0.f, 0.f, 0.f, 0.f};

    const ushort* abase = xg + (size_t)(strip0 * 16 + m) * 64 + q * 8;

    if (t0 >= 2 && t1 <= 61) {
        #pragma unroll
        for (int j = 0; j < 5; ++j) {
            #pragma unroll
            for (int s = 0; s < 2; ++s) {
                const ushort* ab = abase + (ptrdiff_t)(j - 2) * N_DIM * 64 + s * 32;
                s8v af0 = *(const s8v*)ab;
                s8v af1 = *(const s8v*)(ab + 1024);    // +16 rows
                int sg = j * 2 + s;
                #pragma unroll
                for (int c = 0; c < 4; ++c) {
                    s8v bf = *(const s8v*)&Wl[((sg * 4 + c) * 64 + lane) * 8];
                    acc[0][c] = __builtin_amdgcn_mfma_f32_16x16x32_bf16(bf, af0, acc[0][c], 0, 0, 0);
                    acc[1][c] = __builtin_amdgcn_mfma_f32_16x16x32_bf16(bf, af1, acc[1][c], 0, 0, 0);
                }
            }
        }
    } else {
        for (int st = 0; st < 2; ++st) {
            int strip = strip0 + st;
            int t = strip / 125;
            int jlo = (t == 0) ? 2 : ((t == 1) ? 1 : 0);
            int jhi = (t == 63) ? 2 : ((t == 62) ? 3 : 4);
            int tap2off = (t == 0) ? 12288 : ((t == 63) ? 16384 : 0);
            const ushort* ab0 = abase + (size_t)st * 1024;
            for (int j = jlo; j <= jhi; ++j) {
                bool usevar = (j == 2) && (tap2off != 0);
                #pragma unroll
                for (int s = 0; s < 2; ++s) {
                    s8v af = *(const s8v*)(ab0 + (ptrdiff_t)(j - 2) * N_DIM * 64 + s * 32);
                    int sg = j * 2 + s;
                    #pragma unroll
                    for (int c = 0; c < 4; ++c) {
                        int fi = ((sg * 4 + c) * 64 + lane) * 8;
                        s8v bf = usevar ? *(const s8v*)(Wf + tap2off + fi)
                                        : *(const s8v*)&Wl[fi];
                        acc[st][c] = __builtin_amdgcn_mfma_f32_16x16x32_bf16(bf, af, acc[st][c], 0, 0, 0);
                    }
                }
            }
        }
    }

    float ps[16], pq[16];
    #pragma unroll
    for (int i = 0; i < 16; ++i) { ps[i] = 0.f; pq[i] = 0.f; }
    #pragma unroll
    for (int st = 0; st < 2; ++st) {
        int strip = strip0 + st;
        int t = strip / 125;
        int sloc = strip - t * 125;
        int row0 = strip * 16;
        int bcase = (t == 0) ? 0 : ((t == 63) ? 2 : 1);
        float av = a_arr[sloc * 16 + m];
        #pragma unroll
        for (int c = 0; c < 4; ++c) {
            float4 u4 = *(const float4*)&uvec[bcase * 64 + c * 16 + q * 4];
            float4 v4 = *(const float4*)&vvec[bcase * 64 + c * 16 + q * 4];
            float4 r;
            r.x = acc[st][c][0] + av * u4.x + v4.x;
            r.y = acc[st][c][1] + av * u4.y + v4.y;
            r.z = acc[st][c][2] + av * u4.z + v4.z;
            r.w = acc[st][c][3] + av * u4.w + v4.w;
            *(float4*)&out[(size_t)(row0 + m) * 64 + c * 16 + q * 4] = r;
            ps[c * 4 + 0] += r.x; ps[c * 4 + 1] += r.y; ps[c * 4 + 2] += r.z; ps[c * 4 + 3] += r.w;
            pq[c * 4 + 0] += r.x * r.x; pq[c * 4 + 1] += r.y * r.y;
            pq[c * 4 + 2] += r.z * r.z; pq[c * 4 + 3] += r.w * r.w;
        }
    }
    #pragma unroll
    for (int d = 1; d <= 8; d <<= 1) {
        #pragma unroll
        for (int i = 0; i < 16; ++i) {
            ps[i] += __shfl_xor(ps[i], d);
            pq[i] += __shfl_xor(pq[i], d);
        }
    }
    __syncthreads();                 // Wl dead; reuse as sb
    float* sb = (float*)Wl;
    if (tid < 128) sb[tid] = 0.f;
    __syncthreads();
    if (m == 0) {
        #pragma unroll
        for (int i = 0; i < 16; ++i) {
            int ch = (i >> 2) * 16 + q * 4 + (i & 3);
            atomicAdd(&sb[ch], ps[i]);
            atomicAdd(&sb[64 + ch], pq[i]);
        }
    }
    __syncthreads();
    if (tid < 128) atomicAdd(&bnstats[tid], sb[tid]);
}

// ---------------- BN + ReLU, in place; 8000 blocks cover exactly ----------------
__global__ __launch_bounds__(256) void k_bn(float* __restrict__ io,
                                            const float* __restrict__ bnstats,
                                            const float* __restrict__ gamma,
                                            const float* __restrict__ beta) {
    __shared__ float sscale[64], sshift[64];
    int tid = threadIdx.x;
    if (tid < 64) {
        float m = bnstats[tid] * (1.0f / ROWS);
        float v = bnstats[64 + tid] * (1.0f / ROWS) - m * m;
        float sc = gamma[tid] * rsqrtf(v + BN_EPS);
        sscale[tid] = sc;
        sshift[tid] = beta[tid] - m * sc;
    }
    __syncthreads();
    int i4 = blockIdx.x * 256 + tid;     // < 2,048,000 exactly
    float4 v = *(const float4*)(io + (size_t)i4 * 4);
    int c = (i4 * 4) & 63;
    v.x = fmaxf(v.x * sscale[c + 0] + sshift[c + 0], 0.f);
    v.y = fmaxf(v.y * sscale[c + 1] + sshift[c + 1], 0.f);
    v.z = fmaxf(v.z * sscale[c + 2] + sshift[c + 2], 0.f);
    v.w = fmaxf(v.w * sscale[c + 3] + sshift[c + 3], 0.f);
    *(float4*)(io + (size_t)i4 * 4) = v;
}

extern "C" void kernel_launch(void* const* d_in, const int* in_sizes, int n_in,
                              void* d_out, int out_size, void* d_ws, size_t ws_size,
                              hipStream_t stream) {
    const float* x   = (const float*)d_in[0];
    const int*   ei  = (const int*)d_in[1];
    const float* c1w = (const float*)d_in[2];
    const float* c1b = (const float*)d_in[3];
    const float* gw  = (const float*)d_in[4];
    const float* gb  = (const float*)d_in[5];
    const float* c2w = (const float*)d_in[6];
    const float* c2b = (const float*)d_in[7];
    const float* bng = (const float*)d_in[8];
    const float* bnb = (const float*)d_in[9];
    float* out = (float*)d_out;

    // workspace layout
    ushort* xg   = (ushort*)d_ws;                 // ROWS*64 bf16 = 16.4 MB
    ushort* W12f = xg + (size_t)ROWS * 64;        // 28672 (20480 main + 2x4096 variants)
    float*  fb   = (float*)(W12f + 28672);
    float*  Wc1     = fb;                         // 12288
    float*  uvec    = Wc1 + 12288;                // 192
    float*  vvec    = uvec + 192;                 // 192
    float*  a_arr   = vvec + 192;                 // 2000
    float*  dinv    = a_arr + 2000;               // 2000
    float*  bnstats = dinv + 2000;                // 128
    int*    degi    = (int*)(bnstats + 128);      // 2000
    int*    offs    = degi + 2000;                // 2001
    int*    cursor  = offs + 2001;                // 2000
    int*    iend    = cursor + 2000;
    int2*   edat    = (int2*)((char*)iend + (((size_t)iend) % 8 ? 4 : 0)); // 34000 int2

    hipMemsetAsync(degi, 0, sizeof(int) * N_DIM, stream);

    k_pre1<<<173, 256, 0, stream>>>(ei, c1w, gw, degi, Wc1);
    k_pre2<<<1, 1024, 0, stream>>>(degi, dinv, offs, cursor, edat, a_arr, bnstats);
    k_fill<<<125, 256, 0, stream>>>(ei, offs, dinv, cursor, edat, a_arr);
    k_pre3<<<113, 256, 0, stream>>>(Wc1, c2w, c1b, gw, gb, c2b, W12f, uvec, vvec);

    // stage 1: Agg(x) -> xg bf16
    k_gather<<<ROWS / 4, 256, 0, stream>>>(x, offs, edat, xg);
    // stage 2: composed K=5 conv + rank-1 bias + BN stats
    k_conv<<<1000, 256, 0, stream>>>(xg, W12f, uvec, vvec, a_arr, out, bnstats);
    // stage 3: BN + ReLU in place
    k_bn<<<8000, 256, 0, stream>>>(out, bnstats, bng, bnb);
}